// Round 7
// baseline (269.812 us; speedup 1.0000x reference)
//
#include <hip/hip_runtime.h>

#define EPSV 1e-5f

// ---------- fused stage-1 stats: blocks [0,1024) reduce y, [1024,1280) reduce x ----------
__global__ __launch_bounds__(256) void stats_kernel(const float* __restrict__ y,
                                                    const float* __restrict__ x,
                                                    float* __restrict__ part) {
    int bid = blockIdx.x;
    const float* src = (bid < 1024) ? (y + (size_t)bid * 16384)
                                    : (x + (size_t)(bid - 1024) * 16384);
    const float4* p = (const float4*)src;
    float s = 0.f, ss = 0.f;
    #pragma unroll 8
    for (int i = threadIdx.x; i < 4096; i += 256) {
        float4 v = p[i];
        s  += v.x + v.y + v.z + v.w;
        ss += v.x*v.x + v.y*v.y + v.z*v.z + v.w*v.w;
    }
    for (int off = 32; off > 0; off >>= 1) {
        s  += __shfl_down(s, off);
        ss += __shfl_down(ss, off);
    }
    __shared__ float red[8];
    int wid = threadIdx.x >> 6, lane = threadIdx.x & 63;
    if (lane == 0) { red[wid*2] = s; red[wid*2+1] = ss; }
    __syncthreads();
    if (threadIdx.x == 0) {
        part[bid*2+0] = red[0] + red[2] + red[4] + red[6];
        part[bid*2+1] = red[1] + red[3] + red[5] + red[7];
    }
}

// ---------- fused make_eff: blocks [0,128) Q-side, [128,256) K-side ----------
__global__ __launch_bounds__(64) void make_eff_kernel(const float* __restrict__ qw, const float* __restrict__ qb,
                                                      const float* __restrict__ gyw, const float* __restrict__ gyb,
                                                      const float* __restrict__ kw, const float* __restrict__ kb,
                                                      const float* __restrict__ gxw, const float* __restrict__ gxb,
                                                      const float* __restrict__ part,
                                                      float* __restrict__ WeffQ, float* __restrict__ beffQ,
                                                      float* __restrict__ WeffK, float* __restrict__ beffK) {
    int id = blockIdx.x;
    int isK = id >> 7, b = (id >> 5) & 3, e = id & 31;
    const float* w     = isK ? kw  : qw;
    const float* bias  = isK ? kb  : qb;
    const float* gamma = isK ? gxw : gyw;
    const float* beta  = isK ? gxb : gyb;
    float inv_n = isK ? (1.f/32768.f) : (1.f/131072.f);
    float* W  = isK ? WeffK : WeffQ;
    float* be = isK ? beffK : beffQ;
    float partial = 0.f;
    for (int c = threadIdx.x; c < 256; c += 64) {
        int g = c >> 3, grp = b*32 + g;
        float s = 0.f, ss = 0.f;
        if (isK) {
            #pragma unroll
            for (int k2 = 0; k2 < 2; ++k2) {
                s  += part[(1024 + grp*2 + k2)*2 + 0];
                ss += part[(1024 + grp*2 + k2)*2 + 1];
            }
        } else {
            #pragma unroll
            for (int k2 = 0; k2 < 8; ++k2) {
                s  += part[(grp*8 + k2)*2 + 0];
                ss += part[(grp*8 + k2)*2 + 1];
            }
        }
        float mu = s * inv_n;
        float rs = rsqrtf(fmaf(-mu, mu, ss * inv_n) + EPSV);
        float wc = w[e*256 + c];
        float weff = wc * gamma[c] * rs;
        W[((size_t)b*256 + c)*32 + e] = weff;
        partial += wc * beta[c] - weff * mu;
    }
    for (int off = 32; off > 0; off >>= 1) partial += __shfl_down(partial, off);
    if (threadIdx.x == 0) be[b*32 + e] = partial + bias[e];
}

// ---------- 1x1 projection: reg-direct, 16-deep ping-pong pipeline ----------
// Single-wave blocks, 1 px/lane, all 32 e per thread (y read EXACTLY once ->
// no L1/L2 redundancy cap). c processed in ping-pong batches of 16: the 16
// independent global_load_dword of the next batch are issued a full 512-FMA
// (~1024 cyc) ahead of use, hiding even ~900-cyc HBM misses at 1.25 w/SIMD.
// Weights wave-uniform -> s_load (scalar cache, hot after first block).
__global__ __launch_bounds__(64) void proj_kernel(const float* __restrict__ y, const float* __restrict__ x,
                                                  const float* __restrict__ WeffQ, const float* __restrict__ beffQ,
                                                  const float* __restrict__ WeffK, const float* __restrict__ beffK,
                                                  float* __restrict__ qbuf, float* __restrict__ kbuf) {
    int bid = blockIdx.x;
    int isX = bid >= 1024;
    int lb  = isX ? bid - 1024 : bid;
    int b   = isX ? (lb >> 6) : (lb >> 8);
    int pxb = isX ? (lb & 63) : (lb & 255);
    int npix = isX ? 4096 : 16384;
    const float* src   = isX ? x : y;
    const float* WeffT = isX ? WeffK : WeffQ;
    const float* beff  = isX ? beffK : beffQ;
    float* dst = isX ? kbuf : qbuf;

    int pix = pxb * 64 + threadIdx.x;
    float acc[32];
    #pragma unroll
    for (int j = 0; j < 32; ++j) acc[j] = beff[b*32 + j];

    const float* sp = src + (size_t)b*256*npix + pix;
    const float* wb = WeffT + (size_t)b*8192;   // [c][32]

    float va[16], vb[16];
    #pragma unroll
    for (int k = 0; k < 16; ++k) va[k] = sp[(size_t)k*npix];

    #pragma unroll 1
    for (int c0 = 0; c0 < 256; c0 += 32) {
        // prefetch odd half-batch (c0+16 .. c0+31) — always in range
        #pragma unroll
        for (int k = 0; k < 16; ++k) vb[k] = sp[(size_t)(c0 + 16 + k)*npix];
        // compute even half-batch
        #pragma unroll
        for (int k = 0; k < 16; ++k) {
            const float* wr = wb + (c0 + k)*32;
            float t = va[k];
            #pragma unroll
            for (int j = 0; j < 32; ++j) acc[j] = fmaf(t, wr[j], acc[j]);
        }
        // prefetch next even half-batch (c0+32 .. c0+47)
        if (c0 < 224) {
            #pragma unroll
            for (int k = 0; k < 16; ++k) va[k] = sp[(size_t)(c0 + 32 + k)*npix];
        }
        // compute odd half-batch
        #pragma unroll
        for (int k = 0; k < 16; ++k) {
            const float* wr = wb + (c0 + 16 + k)*32;
            float t = vb[k];
            #pragma unroll
            for (int j = 0; j < 32; ++j) acc[j] = fmaf(t, wr[j], acc[j]);
        }
    }

    float* dbase = dst + ((size_t)b*npix + pix)*32;
    #pragma unroll
    for (int j4 = 0; j4 < 8; ++j4) {
        float4 o = {acc[j4*4+0], acc[j4*4+1], acc[j4*4+2], acc[j4*4+3]};
        *(float4*)(dbase + j4*4) = o;
    }
}

// ---------- kernel A: attention weights (e-split, 512-thread blocks) ----------
// Block = 8x8 low-res tile, 8 waves. Wave = parent row h; lane = eq*32 + cl,
// child = h*32 + cl; each half-wave computes a 16-e partial dot, combined via
// one __shfl_xor(a,32) per tap. No sA bounce: direct coalesced stores with
// tap-parity split per half-wave (static indices). 2048 waves = 8/CU.
// Output TRANSPOSED [b][tile(64)][25 tap][256 child].
__global__ __launch_bounds__(512) void attn_weights_kernel(const float* __restrict__ q,   // [B][16384][32]
                                                           const float* __restrict__ kk,  // [B][4096][32]
                                                           float* __restrict__ g_attn)    // [B][64][25][256]
{
    __shared__ __align__(16) float sK[5184];   // [144 pos][36]
    int h0 = blockIdx.y * 8, w0 = blockIdx.x * 8;
    int b = blockIdx.z;
    int tid = threadIdx.x;

    // stage k halo: pos-major, stride 36 (1152 float4 over 512 threads)
    for (int i = tid; i < 1152; i += 512) {
        int pos = i >> 3, e4 = i & 7;
        int r = pos / 12, c = pos - 12*r;
        int gh = h0 + r - 2, gw = w0 + c - 2;
        float4 v = make_float4(0.f, 0.f, 0.f, 0.f);
        if (gh >= 0 && gh < 64 && gw >= 0 && gw < 64)
            v = *(const float4*)(kk + (((size_t)b*4096 + gh*64 + gw)*32 + e4*4));
        *(float4*)&sK[pos*36 + e4*4] = v;
    }

    int wave = tid >> 6;          // 0..7 == parent row h
    int lane = tid & 63;
    int eq   = lane >> 5;         // e-half: [0,16) or [16,32)
    int cl   = lane & 31;         // child within row
    int child = wave*32 + cl;
    int h = wave;
    int u = (cl >> 4) & 1, w = (cl >> 1) & 7, v = cl & 1;

    float qv[16];
    {
        int hh = 2*(h0 + h) + u, ww = 2*(w0 + w) + v;
        const float4* qp = (const float4*)(q + (((size_t)b*16384 + hh*128 + ww)*32 + eq*16));
        #pragma unroll
        for (int i4 = 0; i4 < 4; ++i4) {
            float4 t = qp[i4];
            qv[i4*4+0]=t.x; qv[i4*4+1]=t.y; qv[i4*4+2]=t.z; qv[i4*4+3]=t.w;
        }
    }
    __syncthreads();

    float a[25];
    const float* kbase = &sK[(h*12 + w)*36 + eq*16];
    #pragma unroll
    for (int j = 0; j < 25; ++j) {
        int dy = j / 5, dx = j - 5*dy;
        const float4* kp = (const float4*)(kbase + (dy*12 + dx)*36);
        float acc = 0.f;
        #pragma unroll
        for (int e4 = 0; e4 < 4; ++e4) {
            float4 kv = kp[e4];
            acc = fmaf(qv[e4*4+0], kv.x, acc);
            acc = fmaf(qv[e4*4+1], kv.y, acc);
            acc = fmaf(qv[e4*4+2], kv.z, acc);
            acc = fmaf(qv[e4*4+3], kv.w, acc);
        }
        a[j] = acc;
    }
    // combine e-halves (lane ^ 32 holds the other 16-e partial)
    #pragma unroll
    for (int j = 0; j < 25; ++j) a[j] += __shfl_xor(a[j], 32);

    // softmax (computed redundantly in both halves - identical values)
    float m = -1e30f;
    #pragma unroll
    for (int j = 0; j < 25; ++j) m = fmaxf(m, a[j]);
    float s = 0.f;
    #pragma unroll
    for (int j = 0; j < 25; ++j) { a[j] = __expf(a[j] - m); s += a[j]; }
    float inv = 1.f / s;

    // direct store, tap-parity split: eq0 writes even taps, eq1 odd taps.
    float* gbase = g_attn + ((size_t)b*64 + blockIdx.y*8 + blockIdx.x)*6400 + child;
    if (eq == 0) {
        #pragma unroll
        for (int jj = 0; jj < 13; ++jj) gbase[(2*jj)*256] = a[2*jj] * inv;
    } else {
        #pragma unroll
        for (int jj = 0; jj < 12; ++jj) gbase[(2*jj+1)*256] = a[2*jj+1] * inv;
    }
}

// ---------- kernel B: weighted gather (fine-grained grid for occupancy) ----------
// grid (8,8,64): bz = b*16 + chunk(16 ch). Block = tile, thread = child.
// Attn weights from global (transposed layout -> coalesced dword loads);
// sX [144 pos][16 ch] stride 20 -> b128 reads <=2-way + 4-child broadcast.
__global__ __launch_bounds__(256) void gather_kernel(const float* __restrict__ g_attn, // [B][64][25][256]
                                                     const float* __restrict__ x,      // [B][256][64][64]
                                                     float* __restrict__ out)          // [B][256][128][128]
{
    __shared__ __align__(16) float sX[2880];   // 144*20
    int h0 = blockIdx.y * 8, w0 = blockIdx.x * 8;
    int b = blockIdx.z >> 4, chunk = blockIdx.z & 15;
    int tid = threadIdx.x;

    // per-thread attention weights: coalesced global loads (lane = child)
    float a[25];
    {
        const float* abase = g_attn + ((size_t)b*64 + blockIdx.y*8 + blockIdx.x)*6400 + tid;
        #pragma unroll
        for (int j = 0; j < 25; ++j) a[j] = abase[j*256];
    }

    // stage x chunk: 16 ch x 144 pos, pos-inner (coalesced global)
    for (int i = 0; i < 9; ++i) {
        int t = i*256 + tid;
        int cc = t / 144, pos = t - 144*cc;
        int r = pos / 12, cl = pos - 12*r;
        int gh = h0 + r - 2, gw = w0 + cl - 2;
        float val = 0.f;
        if (gh >= 0 && gh < 64 && gw >= 0 && gw < 64)
            val = x[(((size_t)b*256 + chunk*16 + cc)*64 + gh)*64 + gw];
        sX[pos*20 + cc] = val;
    }

    int h = tid >> 5, u = (tid >> 4) & 1, w = (tid >> 1) & 7, v = tid & 1;
    int hh = 2*(h0 + h) + u, ww = 2*(w0 + w) + v;
    int vbase = (h*12 + w)*20;
    __syncthreads();

    #pragma unroll
    for (int g = 0; g < 4; ++g) {
        float o0 = 0.f, o1 = 0.f, o2 = 0.f, o3 = 0.f;
        const float* xb = &sX[vbase + g*4];
        #pragma unroll
        for (int j = 0; j < 25; ++j) {
            int dy = j / 5, dx = j - 5*dy;
            float4 xv = *(const float4*)(xb + (dy*12 + dx)*20);
            float aw = a[j];
            o0 = fmaf(aw, xv.x, o0);
            o1 = fmaf(aw, xv.y, o1);
            o2 = fmaf(aw, xv.z, o2);
            o3 = fmaf(aw, xv.w, o3);
        }
        size_t ob = (((size_t)b*256 + chunk*16 + g*4)*128 + hh)*128 + ww;
        out[ob]           = o0;
        out[ob + 16384]   = o1;
        out[ob + 32768]   = o2;
        out[ob + 49152]   = o3;
    }
}

extern "C" void kernel_launch(void* const* d_in, const int* in_sizes, int n_in,
                              void* d_out, int out_size, void* d_ws, size_t ws_size,
                              hipStream_t stream) {
    const float* y   = (const float*)d_in[0];
    const float* x   = (const float*)d_in[1];
    const float* gyw = (const float*)d_in[2];
    const float* gyb = (const float*)d_in[3];
    const float* gxw = (const float*)d_in[4];
    const float* gxb = (const float*)d_in[5];
    const float* qw  = (const float*)d_in[6];
    const float* qb  = (const float*)d_in[7];
    const float* kw  = (const float*)d_in[8];
    const float* kb  = (const float*)d_in[9];
    float* out = (float*)d_out;
    float* ws  = (float*)d_ws;

    float* part   = ws;              // 2560
    float* WeffQ  = ws + 2560;       // 32768
    float* beffQ  = ws + 35328;      // 128
    float* WeffK  = ws + 35456;      // 32768
    float* beffK  = ws + 68224;      // 128
    float* qbuf   = ws + 68352;      // 4*16384*32 = 2097152
    float* kbuf   = ws + 2165504;    // 4*4096*32  = 524288
    float* attnbf = ws + 2689792;    // 4*64*6400  = 1638400  (total ~17.3 MB)

    stats_kernel<<<1280, 256, 0, stream>>>(y, x, part);
    make_eff_kernel<<<256, 64, 0, stream>>>(qw, qb, gyw, gyb, kw, kb, gxw, gxb,
                                            part, WeffQ, beffQ, WeffK, beffK);
    proj_kernel<<<1280, 64, 0, stream>>>(y, x, WeffQ, beffQ, WeffK, beffK, qbuf, kbuf);
    attn_weights_kernel<<<dim3(8, 8, 4), 512, 0, stream>>>(qbuf, kbuf, attnbf);
    gather_kernel<<<dim3(8, 8, 64), 256, 0, stream>>>(attnbf, x, out);
}

// Round 8
// 204.788 us; speedup vs baseline: 1.3175x; 1.3175x over previous
//
#include <hip/hip_runtime.h>

#define EPSV 1e-5f

// ---------- fused stage-1 stats: blocks [0,1024) reduce y, [1024,1280) reduce x ----------
__global__ __launch_bounds__(256) void stats_kernel(const float* __restrict__ y,
                                                    const float* __restrict__ x,
                                                    float* __restrict__ part) {
    int bid = blockIdx.x;
    const float* src = (bid < 1024) ? (y + (size_t)bid * 16384)
                                    : (x + (size_t)(bid - 1024) * 16384);
    const float4* p = (const float4*)src;
    float s = 0.f, ss = 0.f;
    #pragma unroll 8
    for (int i = threadIdx.x; i < 4096; i += 256) {
        float4 v = p[i];
        s  += v.x + v.y + v.z + v.w;
        ss += v.x*v.x + v.y*v.y + v.z*v.z + v.w*v.w;
    }
    for (int off = 32; off > 0; off >>= 1) {
        s  += __shfl_down(s, off);
        ss += __shfl_down(ss, off);
    }
    __shared__ float red[8];
    int wid = threadIdx.x >> 6, lane = threadIdx.x & 63;
    if (lane == 0) { red[wid*2] = s; red[wid*2+1] = ss; }
    __syncthreads();
    if (threadIdx.x == 0) {
        part[bid*2+0] = red[0] + red[2] + red[4] + red[6];
        part[bid*2+1] = red[1] + red[3] + red[5] + red[7];
    }
}

// ---------- fused make_eff: blocks [0,128) Q-side, [128,256) K-side ----------
__global__ __launch_bounds__(64) void make_eff_kernel(const float* __restrict__ qw, const float* __restrict__ qb,
                                                      const float* __restrict__ gyw, const float* __restrict__ gyb,
                                                      const float* __restrict__ kw, const float* __restrict__ kb,
                                                      const float* __restrict__ gxw, const float* __restrict__ gxb,
                                                      const float* __restrict__ part,
                                                      float* __restrict__ WeffQ, float* __restrict__ beffQ,
                                                      float* __restrict__ WeffK, float* __restrict__ beffK) {
    int id = blockIdx.x;
    int isK = id >> 7, b = (id >> 5) & 3, e = id & 31;
    const float* w     = isK ? kw  : qw;
    const float* bias  = isK ? kb  : qb;
    const float* gamma = isK ? gxw : gyw;
    const float* beta  = isK ? gxb : gyb;
    float inv_n = isK ? (1.f/32768.f) : (1.f/131072.f);
    float* W  = isK ? WeffK : WeffQ;
    float* be = isK ? beffK : beffQ;
    float partial = 0.f;
    for (int c = threadIdx.x; c < 256; c += 64) {
        int g = c >> 3, grp = b*32 + g;
        float s = 0.f, ss = 0.f;
        if (isK) {
            #pragma unroll
            for (int k2 = 0; k2 < 2; ++k2) {
                s  += part[(1024 + grp*2 + k2)*2 + 0];
                ss += part[(1024 + grp*2 + k2)*2 + 1];
            }
        } else {
            #pragma unroll
            for (int k2 = 0; k2 < 8; ++k2) {
                s  += part[(grp*8 + k2)*2 + 0];
                ss += part[(grp*8 + k2)*2 + 1];
            }
        }
        float mu = s * inv_n;
        float rs = rsqrtf(fmaf(-mu, mu, ss * inv_n) + EPSV);
        float wc = w[e*256 + c];
        float weff = wc * gamma[c] * rs;
        W[((size_t)b*256 + c)*32 + e] = weff;
        partial += wc * beta[c] - weff * mu;
    }
    for (int off = 32; off > 0; off >>= 1) partial += __shfl_down(partial, off);
    if (threadIdx.x == 0) be[b*32 + e] = partial + bias[e];
}

// ---------- fused 1x1 projection, flat 640-block grid (R0 proven version) ----------
// bid<512: y->q (b=bid>>7, 128 px-blocks); bid>=512: x->k (b=(bid-512)>>5, 32 px-blocks)
// 4 waves/block read the SAME pixels (redundancy is L1-hit-free), one e-group
// per wave; 2560 waves = 10/CU of plain TLP hides latency.
__global__ __launch_bounds__(256) void proj_kernel(const float* __restrict__ y, const float* __restrict__ x,
                                                   const float* __restrict__ WeffQ, const float* __restrict__ beffQ,
                                                   const float* __restrict__ WeffK, const float* __restrict__ beffK,
                                                   float* __restrict__ qbuf, float* __restrict__ kbuf) {
    int bid = blockIdx.x;
    int isX = bid >= 512;
    int lb = isX ? bid - 512 : bid;
    int b    = isX ? (lb >> 5) : (lb >> 7);
    int pxb  = isX ? (lb & 31) : (lb & 127);
    int npix = isX ? 4096 : 16384;
    const float* src   = isX ? x : y;
    const float* WeffT = isX ? WeffK : WeffQ;
    const float* beff  = isX ? beffK : beffQ;
    float* dst = isX ? kbuf : qbuf;

    int pix0 = pxb * 128 + (threadIdx.x & 63) * 2;
    int eg = __builtin_amdgcn_readfirstlane(threadIdx.x >> 6);
    const float* wp = WeffT + (size_t)b*256*32 + eg*8;
    float acc[2][8];
    #pragma unroll
    for (int j = 0; j < 8; ++j) {
        float bv = beff[b*32 + eg*8 + j];
        acc[0][j] = bv; acc[1][j] = bv;
    }
    const float* ysrc = src + (size_t)b*256*npix + pix0;
    #pragma unroll 8
    for (int c = 0; c < 256; ++c) {
        float2 t = *(const float2*)(ysrc + (size_t)c*npix);
        #pragma unroll
        for (int j = 0; j < 8; ++j) {
            float wj = wp[c*32 + j];
            acc[0][j] = fmaf(t.x, wj, acc[0][j]);
            acc[1][j] = fmaf(t.y, wj, acc[1][j]);
        }
    }
    float* dbase = dst + ((size_t)b*npix + pix0)*32 + eg*8;
    #pragma unroll
    for (int px = 0; px < 2; ++px) {
        float4 o0 = {acc[px][0], acc[px][1], acc[px][2], acc[px][3]};
        float4 o1 = {acc[px][4], acc[px][5], acc[px][6], acc[px][7]};
        *(float4*)(dbase + px*32 + 0) = o0;
        *(float4*)(dbase + px*32 + 4) = o1;
    }
}

// ---------- kernel A: attention weights (e-split, 512-thread blocks) ----------
// Block = 8x8 low-res tile, 8 waves. Wave = parent row h; lane = eq*32 + cl,
// child = h*32 + cl; each half-wave computes a 16-e partial dot, combined via
// one __shfl_xor(a,32) per tap. No sA bounce: direct coalesced stores with
// tap-parity split per half-wave (static indices). 2048 waves = 8/CU.
// Output TRANSPOSED [b][tile(64)][25 tap][256 child].
__global__ __launch_bounds__(512) void attn_weights_kernel(const float* __restrict__ q,   // [B][16384][32]
                                                           const float* __restrict__ kk,  // [B][4096][32]
                                                           float* __restrict__ g_attn)    // [B][64][25][256]
{
    __shared__ __align__(16) float sK[5184];   // [144 pos][36]
    int h0 = blockIdx.y * 8, w0 = blockIdx.x * 8;
    int b = blockIdx.z;
    int tid = threadIdx.x;

    // stage k halo: pos-major, stride 36 (1152 float4 over 512 threads)
    for (int i = tid; i < 1152; i += 512) {
        int pos = i >> 3, e4 = i & 7;
        int r = pos / 12, c = pos - 12*r;
        int gh = h0 + r - 2, gw = w0 + c - 2;
        float4 v = make_float4(0.f, 0.f, 0.f, 0.f);
        if (gh >= 0 && gh < 64 && gw >= 0 && gw < 64)
            v = *(const float4*)(kk + (((size_t)b*4096 + gh*64 + gw)*32 + e4*4));
        *(float4*)&sK[pos*36 + e4*4] = v;
    }

    int wave = tid >> 6;          // 0..7 == parent row h
    int lane = tid & 63;
    int eq   = lane >> 5;         // e-half: [0,16) or [16,32)
    int cl   = lane & 31;         // child within row
    int child = wave*32 + cl;
    int h = wave;
    int u = (cl >> 4) & 1, w = (cl >> 1) & 7, v = cl & 1;

    float qv[16];
    {
        int hh = 2*(h0 + h) + u, ww = 2*(w0 + w) + v;
        const float4* qp = (const float4*)(q + (((size_t)b*16384 + hh*128 + ww)*32 + eq*16));
        #pragma unroll
        for (int i4 = 0; i4 < 4; ++i4) {
            float4 t = qp[i4];
            qv[i4*4+0]=t.x; qv[i4*4+1]=t.y; qv[i4*4+2]=t.z; qv[i4*4+3]=t.w;
        }
    }
    __syncthreads();

    float a[25];
    const float* kbase = &sK[(h*12 + w)*36 + eq*16];
    #pragma unroll
    for (int j = 0; j < 25; ++j) {
        int dy = j / 5, dx = j - 5*dy;
        const float4* kp = (const float4*)(kbase + (dy*12 + dx)*36);
        float acc = 0.f;
        #pragma unroll
        for (int e4 = 0; e4 < 4; ++e4) {
            float4 kv = kp[e4];
            acc = fmaf(qv[e4*4+0], kv.x, acc);
            acc = fmaf(qv[e4*4+1], kv.y, acc);
            acc = fmaf(qv[e4*4+2], kv.z, acc);
            acc = fmaf(qv[e4*4+3], kv.w, acc);
        }
        a[j] = acc;
    }
    // combine e-halves (lane ^ 32 holds the other 16-e partial)
    #pragma unroll
    for (int j = 0; j < 25; ++j) a[j] += __shfl_xor(a[j], 32);

    // softmax (computed redundantly in both halves - identical values)
    float m = -1e30f;
    #pragma unroll
    for (int j = 0; j < 25; ++j) m = fmaxf(m, a[j]);
    float s = 0.f;
    #pragma unroll
    for (int j = 0; j < 25; ++j) { a[j] = __expf(a[j] - m); s += a[j]; }
    float inv = 1.f / s;

    // direct store, tap-parity split: eq0 writes even taps, eq1 odd taps.
    float* gbase = g_attn + ((size_t)b*64 + blockIdx.y*8 + blockIdx.x)*6400 + child;
    if (eq == 0) {
        #pragma unroll
        for (int jj = 0; jj < 13; ++jj) gbase[(2*jj)*256] = a[2*jj] * inv;
    } else {
        #pragma unroll
        for (int jj = 0; jj < 12; ++jj) gbase[(2*jj+1)*256] = a[2*jj+1] * inv;
    }
}

// ---------- kernel B: weighted gather (fine-grained grid for occupancy) ----------
// grid (8,8,64): bz = b*16 + chunk(16 ch). Block = tile, thread = child.
// Attn weights from global (transposed layout -> coalesced dword loads);
// sX [144 pos][16 ch] stride 20 -> b128 reads <=2-way + 4-child broadcast.
__global__ __launch_bounds__(256) void gather_kernel(const float* __restrict__ g_attn, // [B][64][25][256]
                                                     const float* __restrict__ x,      // [B][256][64][64]
                                                     float* __restrict__ out)          // [B][256][128][128]
{
    __shared__ __align__(16) float sX[2880];   // 144*20
    int h0 = blockIdx.y * 8, w0 = blockIdx.x * 8;
    int b = blockIdx.z >> 4, chunk = blockIdx.z & 15;
    int tid = threadIdx.x;

    // per-thread attention weights: coalesced global loads (lane = child)
    float a[25];
    {
        const float* abase = g_attn + ((size_t)b*64 + blockIdx.y*8 + blockIdx.x)*6400 + tid;
        #pragma unroll
        for (int j = 0; j < 25; ++j) a[j] = abase[j*256];
    }

    // stage x chunk: 16 ch x 144 pos, pos-inner (coalesced global)
    for (int i = 0; i < 9; ++i) {
        int t = i*256 + tid;
        int cc = t / 144, pos = t - 144*cc;
        int r = pos / 12, cl = pos - 12*r;
        int gh = h0 + r - 2, gw = w0 + cl - 2;
        float val = 0.f;
        if (gh >= 0 && gh < 64 && gw >= 0 && gw < 64)
            val = x[(((size_t)b*256 + chunk*16 + cc)*64 + gh)*64 + gw];
        sX[pos*20 + cc] = val;
    }

    int h = tid >> 5, u = (tid >> 4) & 1, w = (tid >> 1) & 7, v = tid & 1;
    int hh = 2*(h0 + h) + u, ww = 2*(w0 + w) + v;
    int vbase = (h*12 + w)*20;
    __syncthreads();

    #pragma unroll
    for (int g = 0; g < 4; ++g) {
        float o0 = 0.f, o1 = 0.f, o2 = 0.f, o3 = 0.f;
        const float* xb = &sX[vbase + g*4];
        #pragma unroll
        for (int j = 0; j < 25; ++j) {
            int dy = j / 5, dx = j - 5*dy;
            float4 xv = *(const float4*)(xb + (dy*12 + dx)*20);
            float aw = a[j];
            o0 = fmaf(aw, xv.x, o0);
            o1 = fmaf(aw, xv.y, o1);
            o2 = fmaf(aw, xv.z, o2);
            o3 = fmaf(aw, xv.w, o3);
        }
        size_t ob = (((size_t)b*256 + chunk*16 + g*4)*128 + hh)*128 + ww;
        out[ob]           = o0;
        out[ob + 16384]   = o1;
        out[ob + 32768]   = o2;
        out[ob + 49152]   = o3;
    }
}

extern "C" void kernel_launch(void* const* d_in, const int* in_sizes, int n_in,
                              void* d_out, int out_size, void* d_ws, size_t ws_size,
                              hipStream_t stream) {
    const float* y   = (const float*)d_in[0];
    const float* x   = (const float*)d_in[1];
    const float* gyw = (const float*)d_in[2];
    const float* gyb = (const float*)d_in[3];
    const float* gxw = (const float*)d_in[4];
    const float* gxb = (const float*)d_in[5];
    const float* qw  = (const float*)d_in[6];
    const float* qb  = (const float*)d_in[7];
    const float* kw  = (const float*)d_in[8];
    const float* kb  = (const float*)d_in[9];
    float* out = (float*)d_out;
    float* ws  = (float*)d_ws;

    float* part   = ws;              // 2560
    float* WeffQ  = ws + 2560;       // 32768
    float* beffQ  = ws + 35328;      // 128
    float* WeffK  = ws + 35456;      // 32768
    float* beffK  = ws + 68224;      // 128
    float* qbuf   = ws + 68352;      // 4*16384*32 = 2097152
    float* kbuf   = ws + 2165504;    // 4*4096*32  = 524288
    float* attnbf = ws + 2689792;    // 4*64*6400  = 1638400  (total ~17.3 MB)

    stats_kernel<<<1280, 256, 0, stream>>>(y, x, part);
    make_eff_kernel<<<256, 64, 0, stream>>>(qw, qb, gyw, gyb, kw, kb, gxw, gxb,
                                            part, WeffQ, beffQ, WeffK, beffK);
    proj_kernel<<<640, 256, 0, stream>>>(y, x, WeffQ, beffQ, WeffK, beffK, qbuf, kbuf);
    attn_weights_kernel<<<dim3(8, 8, 4), 512, 0, stream>>>(qbuf, kbuf, attnbf);
    gather_kernel<<<dim3(8, 8, 64), 256, 0, stream>>>(attnbf, x, out);
}

// Round 9
// 200.759 us; speedup vs baseline: 1.3440x; 1.0201x over previous
//
#include <hip/hip_runtime.h>

#define EPSV 1e-5f

// ---------- fused stage-1 stats: blocks [0,1024) reduce y, [1024,1280) reduce x ----------
__global__ __launch_bounds__(256) void stats_kernel(const float* __restrict__ y,
                                                    const float* __restrict__ x,
                                                    float* __restrict__ part) {
    int bid = blockIdx.x;
    const float* src = (bid < 1024) ? (y + (size_t)bid * 16384)
                                    : (x + (size_t)(bid - 1024) * 16384);
    const float4* p = (const float4*)src;
    float s = 0.f, ss = 0.f;
    #pragma unroll 8
    for (int i = threadIdx.x; i < 4096; i += 256) {
        float4 v = p[i];
        s  += v.x + v.y + v.z + v.w;
        ss += v.x*v.x + v.y*v.y + v.z*v.z + v.w*v.w;
    }
    for (int off = 32; off > 0; off >>= 1) {
        s  += __shfl_down(s, off);
        ss += __shfl_down(ss, off);
    }
    __shared__ float red[8];
    int wid = threadIdx.x >> 6, lane = threadIdx.x & 63;
    if (lane == 0) { red[wid*2] = s; red[wid*2+1] = ss; }
    __syncthreads();
    if (threadIdx.x == 0) {
        part[bid*2+0] = red[0] + red[2] + red[4] + red[6];
        part[bid*2+1] = red[1] + red[3] + red[5] + red[7];
    }
}

// ---------- fused make_eff: blocks [0,128) Q-side, [128,256) K-side ----------
__global__ __launch_bounds__(64) void make_eff_kernel(const float* __restrict__ qw, const float* __restrict__ qb,
                                                      const float* __restrict__ gyw, const float* __restrict__ gyb,
                                                      const float* __restrict__ kw, const float* __restrict__ kb,
                                                      const float* __restrict__ gxw, const float* __restrict__ gxb,
                                                      const float* __restrict__ part,
                                                      float* __restrict__ WeffQ, float* __restrict__ beffQ,
                                                      float* __restrict__ WeffK, float* __restrict__ beffK) {
    int id = blockIdx.x;
    int isK = id >> 7, b = (id >> 5) & 3, e = id & 31;
    const float* w     = isK ? kw  : qw;
    const float* bias  = isK ? kb  : qb;
    const float* gamma = isK ? gxw : gyw;
    const float* beta  = isK ? gxb : gyb;
    float inv_n = isK ? (1.f/32768.f) : (1.f/131072.f);
    float* W  = isK ? WeffK : WeffQ;
    float* be = isK ? beffK : beffQ;
    float partial = 0.f;
    for (int c = threadIdx.x; c < 256; c += 64) {
        int g = c >> 3, grp = b*32 + g;
        float s = 0.f, ss = 0.f;
        if (isK) {
            #pragma unroll
            for (int k2 = 0; k2 < 2; ++k2) {
                s  += part[(1024 + grp*2 + k2)*2 + 0];
                ss += part[(1024 + grp*2 + k2)*2 + 1];
            }
        } else {
            #pragma unroll
            for (int k2 = 0; k2 < 8; ++k2) {
                s  += part[(grp*8 + k2)*2 + 0];
                ss += part[(grp*8 + k2)*2 + 1];
            }
        }
        float mu = s * inv_n;
        float rs = rsqrtf(fmaf(-mu, mu, ss * inv_n) + EPSV);
        float wc = w[e*256 + c];
        float weff = wc * gamma[c] * rs;
        W[((size_t)b*256 + c)*32 + e] = weff;
        partial += wc * beta[c] - weff * mu;
    }
    for (int off = 32; off > 0; off >>= 1) partial += __shfl_down(partial, off);
    if (threadIdx.x == 0) be[b*32 + e] = partial + bias[e];
}

// ---------- fused 1x1 projection, flat 640-block grid (R0 proven version) ----------
// bid<512: y->q (b=bid>>7, 128 px-blocks); bid>=512: x->k (b=(bid-512)>>5, 32 px-blocks)
// 4 waves/block read the SAME pixels (redundancy is L1-hit-free), one e-group
// per wave; 2560 waves = 10/CU of plain TLP hides latency.
__global__ __launch_bounds__(256) void proj_kernel(const float* __restrict__ y, const float* __restrict__ x,
                                                   const float* __restrict__ WeffQ, const float* __restrict__ beffQ,
                                                   const float* __restrict__ WeffK, const float* __restrict__ beffK,
                                                   float* __restrict__ qbuf, float* __restrict__ kbuf) {
    int bid = blockIdx.x;
    int isX = bid >= 512;
    int lb = isX ? bid - 512 : bid;
    int b    = isX ? (lb >> 5) : (lb >> 7);
    int pxb  = isX ? (lb & 31) : (lb & 127);
    int npix = isX ? 4096 : 16384;
    const float* src   = isX ? x : y;
    const float* WeffT = isX ? WeffK : WeffQ;
    const float* beff  = isX ? beffK : beffQ;
    float* dst = isX ? kbuf : qbuf;

    int pix0 = pxb * 128 + (threadIdx.x & 63) * 2;
    int eg = __builtin_amdgcn_readfirstlane(threadIdx.x >> 6);
    const float* wp = WeffT + (size_t)b*256*32 + eg*8;
    float acc[2][8];
    #pragma unroll
    for (int j = 0; j < 8; ++j) {
        float bv = beff[b*32 + eg*8 + j];
        acc[0][j] = bv; acc[1][j] = bv;
    }
    const float* ysrc = src + (size_t)b*256*npix + pix0;
    #pragma unroll 8
    for (int c = 0; c < 256; ++c) {
        float2 t = *(const float2*)(ysrc + (size_t)c*npix);
        #pragma unroll
        for (int j = 0; j < 8; ++j) {
            float wj = wp[c*32 + j];
            acc[0][j] = fmaf(t.x, wj, acc[0][j]);
            acc[1][j] = fmaf(t.y, wj, acc[1][j]);
        }
    }
    float* dbase = dst + ((size_t)b*npix + pix0)*32 + eg*8;
    #pragma unroll
    for (int px = 0; px < 2; ++px) {
        float4 o0 = {acc[px][0], acc[px][1], acc[px][2], acc[px][3]};
        float4 o1 = {acc[px][4], acc[px][5], acc[px][6], acc[px][7]};
        *(float4*)(dbase + px*32 + 0) = o0;
        *(float4*)(dbase + px*32 + 4) = o1;
    }
}

// ---------- kernel A: attention weights (e-split, 512-thread blocks) ----------
// Block = 8x8 low-res tile, 8 waves. Wave = parent row h; lane = eq*32 + cl,
// child = h*32 + cl; each half-wave computes a 16-e partial dot, combined via
// one __shfl_xor(a,32) per tap. No sA bounce: direct coalesced stores with
// tap-parity split per half-wave (static indices). 2048 waves = 8/CU.
// Output TRANSPOSED [b][tile(64)][25 tap][256 child].
__global__ __launch_bounds__(512) void attn_weights_kernel(const float* __restrict__ q,   // [B][16384][32]
                                                           const float* __restrict__ kk,  // [B][4096][32]
                                                           float* __restrict__ g_attn)    // [B][64][25][256]
{
    __shared__ __align__(16) float sK[5184];   // [144 pos][36]
    int h0 = blockIdx.y * 8, w0 = blockIdx.x * 8;
    int b = blockIdx.z;
    int tid = threadIdx.x;

    // stage k halo: pos-major, stride 36 (1152 float4 over 512 threads)
    for (int i = tid; i < 1152; i += 512) {
        int pos = i >> 3, e4 = i & 7;
        int r = pos / 12, c = pos - 12*r;
        int gh = h0 + r - 2, gw = w0 + c - 2;
        float4 v = make_float4(0.f, 0.f, 0.f, 0.f);
        if (gh >= 0 && gh < 64 && gw >= 0 && gw < 64)
            v = *(const float4*)(kk + (((size_t)b*4096 + gh*64 + gw)*32 + e4*4));
        *(float4*)&sK[pos*36 + e4*4] = v;
    }

    int wave = tid >> 6;          // 0..7 == parent row h
    int lane = tid & 63;
    int eq   = lane >> 5;         // e-half: [0,16) or [16,32)
    int cl   = lane & 31;         // child within row
    int child = wave*32 + cl;
    int h = wave;
    int u = (cl >> 4) & 1, w = (cl >> 1) & 7, v = cl & 1;

    float qv[16];
    {
        int hh = 2*(h0 + h) + u, ww = 2*(w0 + w) + v;
        const float4* qp = (const float4*)(q + (((size_t)b*16384 + hh*128 + ww)*32 + eq*16));
        #pragma unroll
        for (int i4 = 0; i4 < 4; ++i4) {
            float4 t = qp[i4];
            qv[i4*4+0]=t.x; qv[i4*4+1]=t.y; qv[i4*4+2]=t.z; qv[i4*4+3]=t.w;
        }
    }
    __syncthreads();

    float a[25];
    const float* kbase = &sK[(h*12 + w)*36 + eq*16];
    #pragma unroll
    for (int j = 0; j < 25; ++j) {
        int dy = j / 5, dx = j - 5*dy;
        const float4* kp = (const float4*)(kbase + (dy*12 + dx)*36);
        float acc = 0.f;
        #pragma unroll
        for (int e4 = 0; e4 < 4; ++e4) {
            float4 kv = kp[e4];
            acc = fmaf(qv[e4*4+0], kv.x, acc);
            acc = fmaf(qv[e4*4+1], kv.y, acc);
            acc = fmaf(qv[e4*4+2], kv.z, acc);
            acc = fmaf(qv[e4*4+3], kv.w, acc);
        }
        a[j] = acc;
    }
    // combine e-halves (lane ^ 32 holds the other 16-e partial)
    #pragma unroll
    for (int j = 0; j < 25; ++j) a[j] += __shfl_xor(a[j], 32);

    // softmax (computed redundantly in both halves - identical values)
    float m = -1e30f;
    #pragma unroll
    for (int j = 0; j < 25; ++j) m = fmaxf(m, a[j]);
    float s = 0.f;
    #pragma unroll
    for (int j = 0; j < 25; ++j) { a[j] = __expf(a[j] - m); s += a[j]; }
    float inv = 1.f / s;

    // direct store, tap-parity split: eq0 writes even taps, eq1 odd taps.
    float* gbase = g_attn + ((size_t)b*64 + blockIdx.y*8 + blockIdx.x)*6400 + child;
    if (eq == 0) {
        #pragma unroll
        for (int jj = 0; jj < 13; ++jj) gbase[(2*jj)*256] = a[2*jj] * inv;
    } else {
        #pragma unroll
        for (int jj = 0; jj < 12; ++jj) gbase[(2*jj+1)*256] = a[2*jj+1] * inv;
    }
}

// ---------- kernel B: weighted gather (fine grid + XCD-locality swizzle) ----------
// Flat grid 4096. xcd = bid&7 (round-robin dispatch), swz = xcd*512 + bid>>3:
// each XCD gets 512 consecutive work units = 32 (b,tile) groups x 16 chunks,
// chunk-fastest -> all 16 blocks sharing one attn map (25.6 KB, read 16x)
// run consecutively on ONE XCD -> map is L2-resident (32 maps = 800 KB << 4 MB).
// Block = tile, thread = child. sX [144 pos][16 ch] stride 20.
__global__ __launch_bounds__(256) void gather_kernel(const float* __restrict__ g_attn, // [B][64][25][256]
                                                     const float* __restrict__ x,      // [B][256][64][64]
                                                     float* __restrict__ out)          // [B][256][128][128]
{
    __shared__ __align__(16) float sX[2880];   // 144*20
    int bid = blockIdx.x;
    int swz = (bid & 7) * 512 + (bid >> 3);   // bijective: 4096 = 8*512
    int chunk = swz & 15;
    int grp   = swz >> 4;        // 0..255
    int b     = grp >> 6;
    int tile  = grp & 63;
    int h0 = (tile >> 3) * 8, w0 = (tile & 7) * 8;
    int tid = threadIdx.x;

    // per-thread attention weights: coalesced global loads (lane = child)
    float a[25];
    {
        const float* abase = g_attn + ((size_t)b*64 + tile)*6400 + tid;
        #pragma unroll
        for (int j = 0; j < 25; ++j) a[j] = abase[j*256];
    }

    // stage x chunk: 16 ch x 144 pos, pos-inner (coalesced global)
    for (int i = 0; i < 9; ++i) {
        int t = i*256 + tid;
        int cc = t / 144, pos = t - 144*cc;
        int r = pos / 12, cl = pos - 12*r;
        int gh = h0 + r - 2, gw = w0 + cl - 2;
        float val = 0.f;
        if (gh >= 0 && gh < 64 && gw >= 0 && gw < 64)
            val = x[(((size_t)b*256 + chunk*16 + cc)*64 + gh)*64 + gw];
        sX[pos*20 + cc] = val;
    }

    int h = tid >> 5, u = (tid >> 4) & 1, w = (tid >> 1) & 7, v = tid & 1;
    int hh = 2*(h0 + h) + u, ww = 2*(w0 + w) + v;
    int vbase = (h*12 + w)*20;
    __syncthreads();

    #pragma unroll
    for (int g = 0; g < 4; ++g) {
        float o0 = 0.f, o1 = 0.f, o2 = 0.f, o3 = 0.f;
        const float* xb = &sX[vbase + g*4];
        #pragma unroll
        for (int j = 0; j < 25; ++j) {
            int dy = j / 5, dx = j - 5*dy;
            float4 xv = *(const float4*)(xb + (dy*12 + dx)*20);
            float aw = a[j];
            o0 = fmaf(aw, xv.x, o0);
            o1 = fmaf(aw, xv.y, o1);
            o2 = fmaf(aw, xv.z, o2);
            o3 = fmaf(aw, xv.w, o3);
        }
        size_t ob = (((size_t)b*256 + chunk*16 + g*4)*128 + hh)*128 + ww;
        out[ob]           = o0;
        out[ob + 16384]   = o1;
        out[ob + 32768]   = o2;
        out[ob + 49152]   = o3;
    }
}

extern "C" void kernel_launch(void* const* d_in, const int* in_sizes, int n_in,
                              void* d_out, int out_size, void* d_ws, size_t ws_size,
                              hipStream_t stream) {
    const float* y   = (const float*)d_in[0];
    const float* x   = (const float*)d_in[1];
    const float* gyw = (const float*)d_in[2];
    const float* gyb = (const float*)d_in[3];
    const float* gxw = (const float*)d_in[4];
    const float* gxb = (const float*)d_in[5];
    const float* qw  = (const float*)d_in[6];
    const float* qb  = (const float*)d_in[7];
    const float* kw  = (const float*)d_in[8];
    const float* kb  = (const float*)d_in[9];
    float* out = (float*)d_out;
    float* ws  = (float*)d_ws;

    float* part   = ws;              // 2560
    float* WeffQ  = ws + 2560;       // 32768
    float* beffQ  = ws + 35328;      // 128
    float* WeffK  = ws + 35456;      // 32768
    float* beffK  = ws + 68224;      // 128
    float* qbuf   = ws + 68352;      // 4*16384*32 = 2097152
    float* kbuf   = ws + 2165504;    // 4*4096*32  = 524288
    float* attnbf = ws + 2689792;    // 4*64*6400  = 1638400  (total ~17.3 MB)

    stats_kernel<<<1280, 256, 0, stream>>>(y, x, part);
    make_eff_kernel<<<256, 64, 0, stream>>>(qw, qb, gyw, gyb, kw, kb, gxw, gxb,
                                            part, WeffQ, beffQ, WeffK, beffK);
    proj_kernel<<<640, 256, 0, stream>>>(y, x, WeffQ, beffQ, WeffK, beffK, qbuf, kbuf);
    attn_weights_kernel<<<dim3(8, 8, 4), 512, 0, stream>>>(qbuf, kbuf, attnbf);
    gather_kernel<<<4096, 256, 0, stream>>>(attnbf, x, out);
}

// Round 10
// 198.361 us; speedup vs baseline: 1.3602x; 1.0121x over previous
//
#include <hip/hip_runtime.h>

#define EPSV 1e-5f

// ---------- fused stage-1 stats: blocks [0,1024) reduce y, [1024,1280) reduce x ----------
__global__ __launch_bounds__(256) void stats_kernel(const float* __restrict__ y,
                                                    const float* __restrict__ x,
                                                    float* __restrict__ part) {
    int bid = blockIdx.x;
    const float* src = (bid < 1024) ? (y + (size_t)bid * 16384)
                                    : (x + (size_t)(bid - 1024) * 16384);
    const float4* p = (const float4*)src;
    float s = 0.f, ss = 0.f;
    #pragma unroll 8
    for (int i = threadIdx.x; i < 4096; i += 256) {
        float4 v = p[i];
        s  += v.x + v.y + v.z + v.w;
        ss += v.x*v.x + v.y*v.y + v.z*v.z + v.w*v.w;
    }
    for (int off = 32; off > 0; off >>= 1) {
        s  += __shfl_down(s, off);
        ss += __shfl_down(ss, off);
    }
    __shared__ float red[8];
    int wid = threadIdx.x >> 6, lane = threadIdx.x & 63;
    if (lane == 0) { red[wid*2] = s; red[wid*2+1] = ss; }
    __syncthreads();
    if (threadIdx.x == 0) {
        part[bid*2+0] = red[0] + red[2] + red[4] + red[6];
        part[bid*2+1] = red[1] + red[3] + red[5] + red[7];
    }
}

// ---------- fused 1x1 projection with inlined make_eff prologue ----------
// Same flat 640-block grid / 4-wave structure as the proven R0 version.
// Prologue: each wave computes its OWN 2048-entry Weff slice (c = lane+64k,
// its 8 e's) into a wave-private 8 KB LDS region (no __syncthreads needed;
// lgkmcnt orders ds_write -> ds_read within the wave), and beff via shfl_xor
// reduction. Inner loop identical, weights read from LDS (uniform broadcast).
// Eliminates the make_eff kernel + 1 launch gap + Weff global round-trip.
__global__ __launch_bounds__(256) void proj_kernel(const float* __restrict__ y, const float* __restrict__ x,
                                                   const float* __restrict__ qw, const float* __restrict__ qb,
                                                   const float* __restrict__ kw, const float* __restrict__ kb,
                                                   const float* __restrict__ gyw, const float* __restrict__ gyb,
                                                   const float* __restrict__ gxw, const float* __restrict__ gxb,
                                                   const float* __restrict__ part,
                                                   float* __restrict__ qbuf, float* __restrict__ kbuf) {
    __shared__ __align__(16) float sW[4][2048];   // [wave][c*8 + jj], 32 KB
    int bid = blockIdx.x;
    int isX = bid >= 512;
    int lb = isX ? bid - 512 : bid;
    int b    = isX ? (lb >> 5) : (lb >> 7);
    int pxb  = isX ? (lb & 31) : (lb & 127);
    int npix = isX ? 4096 : 16384;
    const float* src   = isX ? x : y;
    const float* w     = isX ? kw  : qw;
    const float* bias  = isX ? kb  : qb;
    const float* gamma = isX ? gxw : gyw;
    const float* beta  = isX ? gxb : gyb;
    float inv_n = isX ? (1.f/32768.f) : (1.f/131072.f);
    float* dst = isX ? kbuf : qbuf;

    int lane = threadIdx.x & 63;
    int eg   = __builtin_amdgcn_readfirstlane(threadIdx.x >> 6);
    float* sWb = sW[eg];

    // ---- prologue: build this wave's Weff slice + beff (make_eff inlined) ----
    float bcon[8];
    #pragma unroll
    for (int jj = 0; jj < 8; ++jj) bcon[jj] = 0.f;
    #pragma unroll
    for (int k = 0; k < 4; ++k) {
        int c = lane + 64*k;
        int grp = b*32 + (c >> 3);
        float s = 0.f, ss = 0.f;
        if (isX) {
            #pragma unroll
            for (int k2 = 0; k2 < 2; ++k2) {
                s  += part[(1024 + grp*2 + k2)*2 + 0];
                ss += part[(1024 + grp*2 + k2)*2 + 1];
            }
        } else {
            #pragma unroll
            for (int k2 = 0; k2 < 8; ++k2) {
                s  += part[(grp*8 + k2)*2 + 0];
                ss += part[(grp*8 + k2)*2 + 1];
            }
        }
        float mu = s * inv_n;
        float rs = rsqrtf(fmaf(-mu, mu, ss * inv_n) + EPSV);
        float gm = gamma[c], bt = beta[c];
        float wv[8];
        #pragma unroll
        for (int jj = 0; jj < 8; ++jj) {
            float wc = w[(eg*8 + jj)*256 + c];       // coalesced per jj
            float weff = wc * gm * rs;
            wv[jj] = weff;
            bcon[jj] += wc * bt - weff * mu;
        }
        float4 o0 = {wv[0], wv[1], wv[2], wv[3]};
        float4 o1 = {wv[4], wv[5], wv[6], wv[7]};
        *(float4*)&sWb[c*8 + 0] = o0;
        *(float4*)&sWb[c*8 + 4] = o1;
    }
    // wave-wide sum of bcon (all 64 lanes -> every lane holds the total)
    #pragma unroll
    for (int off = 32; off > 0; off >>= 1) {
        #pragma unroll
        for (int jj = 0; jj < 8; ++jj) bcon[jj] += __shfl_xor(bcon[jj], off);
    }

    // ---- main loop: identical structure to the proven R0 proj ----
    int pix0 = pxb * 128 + lane * 2;
    float acc[2][8];
    #pragma unroll
    for (int j = 0; j < 8; ++j) {
        float bv = bcon[j] + bias[eg*8 + j];
        acc[0][j] = bv; acc[1][j] = bv;
    }
    const float* ysrc = src + (size_t)b*256*npix + pix0;
    #pragma unroll 8
    for (int c = 0; c < 256; ++c) {
        float2 t = *(const float2*)(ysrc + (size_t)c*npix);
        const float* wp = &sWb[c*8];
        #pragma unroll
        for (int j = 0; j < 8; ++j) {
            float wj = wp[j];
            acc[0][j] = fmaf(t.x, wj, acc[0][j]);
            acc[1][j] = fmaf(t.y, wj, acc[1][j]);
        }
    }
    float* dbase = dst + ((size_t)b*npix + pix0)*32 + eg*8;
    #pragma unroll
    for (int px = 0; px < 2; ++px) {
        float4 o0 = {acc[px][0], acc[px][1], acc[px][2], acc[px][3]};
        float4 o1 = {acc[px][4], acc[px][5], acc[px][6], acc[px][7]};
        *(float4*)(dbase + px*32 + 0) = o0;
        *(float4*)(dbase + px*32 + 4) = o1;
    }
}

// ---------- kernel A: attention weights (e-split, 512-thread blocks) ----------
// Block = 8x8 low-res tile, 8 waves. Wave = parent row h; lane = eq*32 + cl,
// child = h*32 + cl; each half-wave computes a 16-e partial dot, combined via
// one __shfl_xor(a,32) per tap. No sA bounce: direct coalesced stores with
// tap-parity split per half-wave (static indices). 2048 waves = 8/CU.
// Output TRANSPOSED [b][tile(64)][25 tap][256 child].
__global__ __launch_bounds__(512) void attn_weights_kernel(const float* __restrict__ q,   // [B][16384][32]
                                                           const float* __restrict__ kk,  // [B][4096][32]
                                                           float* __restrict__ g_attn)    // [B][64][25][256]
{
    __shared__ __align__(16) float sK[5184];   // [144 pos][36]
    int h0 = blockIdx.y * 8, w0 = blockIdx.x * 8;
    int b = blockIdx.z;
    int tid = threadIdx.x;

    // stage k halo: pos-major, stride 36 (1152 float4 over 512 threads)
    for (int i = tid; i < 1152; i += 512) {
        int pos = i >> 3, e4 = i & 7;
        int r = pos / 12, c = pos - 12*r;
        int gh = h0 + r - 2, gw = w0 + c - 2;
        float4 v = make_float4(0.f, 0.f, 0.f, 0.f);
        if (gh >= 0 && gh < 64 && gw >= 0 && gw < 64)
            v = *(const float4*)(kk + (((size_t)b*4096 + gh*64 + gw)*32 + e4*4));
        *(float4*)&sK[pos*36 + e4*4] = v;
    }

    int wave = tid >> 6;          // 0..7 == parent row h
    int lane = tid & 63;
    int eq   = lane >> 5;         // e-half: [0,16) or [16,32)
    int cl   = lane & 31;         // child within row
    int child = wave*32 + cl;
    int h = wave;
    int u = (cl >> 4) & 1, w = (cl >> 1) & 7, v = cl & 1;

    float qv[16];
    {
        int hh = 2*(h0 + h) + u, ww = 2*(w0 + w) + v;
        const float4* qp = (const float4*)(q + (((size_t)b*16384 + hh*128 + ww)*32 + eq*16));
        #pragma unroll
        for (int i4 = 0; i4 < 4; ++i4) {
            float4 t = qp[i4];
            qv[i4*4+0]=t.x; qv[i4*4+1]=t.y; qv[i4*4+2]=t.z; qv[i4*4+3]=t.w;
        }
    }
    __syncthreads();

    float a[25];
    const float* kbase = &sK[(h*12 + w)*36 + eq*16];
    #pragma unroll
    for (int j = 0; j < 25; ++j) {
        int dy = j / 5, dx = j - 5*dy;
        const float4* kp = (const float4*)(kbase + (dy*12 + dx)*36);
        float acc = 0.f;
        #pragma unroll
        for (int e4 = 0; e4 < 4; ++e4) {
            float4 kv = kp[e4];
            acc = fmaf(qv[e4*4+0], kv.x, acc);
            acc = fmaf(qv[e4*4+1], kv.y, acc);
            acc = fmaf(qv[e4*4+2], kv.z, acc);
            acc = fmaf(qv[e4*4+3], kv.w, acc);
        }
        a[j] = acc;
    }
    // combine e-halves (lane ^ 32 holds the other 16-e partial)
    #pragma unroll
    for (int j = 0; j < 25; ++j) a[j] += __shfl_xor(a[j], 32);

    // softmax (computed redundantly in both halves - identical values)
    float m = -1e30f;
    #pragma unroll
    for (int j = 0; j < 25; ++j) m = fmaxf(m, a[j]);
    float s = 0.f;
    #pragma unroll
    for (int j = 0; j < 25; ++j) { a[j] = __expf(a[j] - m); s += a[j]; }
    float inv = 1.f / s;

    // direct store, tap-parity split: eq0 writes even taps, eq1 odd taps.
    float* gbase = g_attn + ((size_t)b*64 + blockIdx.y*8 + blockIdx.x)*6400 + child;
    if (eq == 0) {
        #pragma unroll
        for (int jj = 0; jj < 13; ++jj) gbase[(2*jj)*256] = a[2*jj] * inv;
    } else {
        #pragma unroll
        for (int jj = 0; jj < 12; ++jj) gbase[(2*jj+1)*256] = a[2*jj+1] * inv;
    }
}

// ---------- kernel B: weighted gather (fine grid + XCD-locality swizzle) ----------
// Flat grid 4096. xcd = bid&7 (round-robin dispatch), swz = xcd*512 + bid>>3:
// each XCD gets 512 consecutive work units = 32 (b,tile) groups x 16 chunks,
// chunk-fastest -> all 16 blocks sharing one attn map (25.6 KB, read 16x)
// run consecutively on ONE XCD -> map is L2-resident (32 maps = 800 KB << 4 MB).
// Block = tile, thread = child. sX [144 pos][16 ch] stride 20.
__global__ __launch_bounds__(256) void gather_kernel(const float* __restrict__ g_attn, // [B][64][25][256]
                                                     const float* __restrict__ x,      // [B][256][64][64]
                                                     float* __restrict__ out)          // [B][256][128][128]
{
    __shared__ __align__(16) float sX[2880];   // 144*20
    int bid = blockIdx.x;
    int swz = (bid & 7) * 512 + (bid >> 3);   // bijective: 4096 = 8*512
    int chunk = swz & 15;
    int grp   = swz >> 4;        // 0..255
    int b     = grp >> 6;
    int tile  = grp & 63;
    int h0 = (tile >> 3) * 8, w0 = (tile & 7) * 8;
    int tid = threadIdx.x;

    // per-thread attention weights: coalesced global loads (lane = child)
    float a[25];
    {
        const float* abase = g_attn + ((size_t)b*64 + tile)*6400 + tid;
        #pragma unroll
        for (int j = 0; j < 25; ++j) a[j] = abase[j*256];
    }

    // stage x chunk: 16 ch x 144 pos, pos-inner (coalesced global)
    for (int i = 0; i < 9; ++i) {
        int t = i*256 + tid;
        int cc = t / 144, pos = t - 144*cc;
        int r = pos / 12, cl = pos - 12*r;
        int gh = h0 + r - 2, gw = w0 + cl - 2;
        float val = 0.f;
        if (gh >= 0 && gh < 64 && gw >= 0 && gw < 64)
            val = x[(((size_t)b*256 + chunk*16 + cc)*64 + gh)*64 + gw];
        sX[pos*20 + cc] = val;
    }

    int h = tid >> 5, u = (tid >> 4) & 1, w = (tid >> 1) & 7, v = tid & 1;
    int hh = 2*(h0 + h) + u, ww = 2*(w0 + w) + v;
    int vbase = (h*12 + w)*20;
    __syncthreads();

    #pragma unroll
    for (int g = 0; g < 4; ++g) {
        float o0 = 0.f, o1 = 0.f, o2 = 0.f, o3 = 0.f;
        const float* xb = &sX[vbase + g*4];
        #pragma unroll
        for (int j = 0; j < 25; ++j) {
            int dy = j / 5, dx = j - 5*dy;
            float4 xv = *(const float4*)(xb + (dy*12 + dx)*20);
            float aw = a[j];
            o0 = fmaf(aw, xv.x, o0);
            o1 = fmaf(aw, xv.y, o1);
            o2 = fmaf(aw, xv.z, o2);
            o3 = fmaf(aw, xv.w, o3);
        }
        size_t ob = (((size_t)b*256 + chunk*16 + g*4)*128 + hh)*128 + ww;
        out[ob]           = o0;
        out[ob + 16384]   = o1;
        out[ob + 32768]   = o2;
        out[ob + 49152]   = o3;
    }
}

extern "C" void kernel_launch(void* const* d_in, const int* in_sizes, int n_in,
                              void* d_out, int out_size, void* d_ws, size_t ws_size,
                              hipStream_t stream) {
    const float* y   = (const float*)d_in[0];
    const float* x   = (const float*)d_in[1];
    const float* gyw = (const float*)d_in[2];
    const float* gyb = (const float*)d_in[3];
    const float* gxw = (const float*)d_in[4];
    const float* gxb = (const float*)d_in[5];
    const float* qw  = (const float*)d_in[6];
    const float* qb  = (const float*)d_in[7];
    const float* kw  = (const float*)d_in[8];
    const float* kb  = (const float*)d_in[9];
    float* out = (float*)d_out;
    float* ws  = (float*)d_ws;

    float* part   = ws;              // 2560
    float* qbuf   = ws + 68352;      // 4*16384*32 = 2097152  (offsets kept stable)
    float* kbuf   = ws + 2165504;    // 4*4096*32  = 524288
    float* attnbf = ws + 2689792;    // 4*64*6400  = 1638400  (total ~17.3 MB)

    stats_kernel<<<1280, 256, 0, stream>>>(y, x, part);
    proj_kernel<<<640, 256, 0, stream>>>(y, x, qw, qb, kw, kb, gyw, gyb, gxw, gxb,
                                         part, qbuf, kbuf);
    attn_weights_kernel<<<dim3(8, 8, 4), 512, 0, stream>>>(qbuf, kbuf, attnbf);
    gather_kernel<<<4096, 256, 0, stream>>>(attnbf, x, out);
}